// Round 6
// baseline (927.074 us; speedup 1.0000x reference)
//
#include <hip/hip_runtime.h>

// Tree_Net: B=256 batches, L=64 leaves, D=1024 dims, N=127 nodes, S=63 compose
// steps, C=500 classes. Pipeline:
//   K1 leaf_init : gather emb rows, mask, L2-normalize -> vec_f32[B][127][1024]
//   K3 conv_w    : lin_w fp32 [500][1024] -> bf16 padded [512][1024] (pad rows=0)
//   K2 tree_scan : 63 sequential circular-correlation+normalize steps per batch
//                  (fp32, one block per batch, direct O(D^2) evaluation)
//   K4 gemm_out  : bf16 MFMA 16x16x32 GEMM (A staged fp32->bf16 in-kernel),
//                  + bias + sigmoid -> out fp32 [B*127][500]
// Workspace: vec_f32 = 133,169,152 B ; lin_w bf16 = 1,048,576 B ; total 128 MiB.

#define BATCH 256
#define LLEN 64
#define DDIM 1024
#define NNODE 127
#define NSTEP 63
#define NCLS 500
#define NCLSP 512

// padded LDS index: +1 float per 32 -> stride-16-float lane access is 2-way (free)
#define PAD(i) ((i) + ((i) >> 5))

typedef __attribute__((ext_vector_type(8))) __bf16 bf16x8_t;
typedef __attribute__((ext_vector_type(4))) float f32x4_t;

__device__ __forceinline__ short f2bf(float f) {
  union { float f; unsigned u; } v; v.f = f;
  unsigned r = v.u + 0x7FFFu + ((v.u >> 16) & 1u);  // RNE, matches HW cvt
  return (short)(r >> 16);
}

// ---------------- K1: leaves gather + mask + normalize; internals zeroed ----
__global__ __launch_bounds__(256) void leaf_init(
    const int* __restrict__ ids, const int* __restrict__ cmask,
    const float* __restrict__ emb, float* __restrict__ vec) {
  const int n = blockIdx.x, b = blockIdx.y, t = threadIdx.x;
  float* dst = vec + ((size_t)b * NNODE + n) * DDIM + 4 * t;
  if (n >= LLEN) {  // internal node: zero (uniform per block, safe early return)
    float4 z = make_float4(0.f, 0.f, 0.f, 0.f);
    *(float4*)dst = z;
    return;
  }
  __shared__ float sred[4];
  const int id = ids[b * LLEN + n];
  const int m = cmask[b * LLEN + n];
  float4 v = make_float4(0.f, 0.f, 0.f, 0.f);
  if (m > 0) v = *(const float4*)(emb + (size_t)id * DDIM + 4 * t);
  float ss = v.x * v.x + v.y * v.y + v.z * v.z + v.w * v.w;
#pragma unroll
  for (int off = 32; off > 0; off >>= 1) ss += __shfl_xor(ss, off);
  if ((t & 63) == 0) sred[t >> 6] = ss;
  __syncthreads();
  const float tot = sred[0] + sred[1] + sred[2] + sred[3];
  const float rn = 1.f / (sqrtf(tot) + 1e-6f);
  v.x *= rn; v.y *= rn; v.z *= rn; v.w *= rn;
  *(float4*)dst = v;
}

// ---------------- K3: lin_w fp32 -> bf16, padded to 512 rows ----------------
__global__ __launch_bounds__(256) void conv_w(const float* __restrict__ w,
                                              short* __restrict__ wb) {
  const int i = (blockIdx.x * 256 + threadIdx.x) * 4;
  short4 o;
  if (i < NCLS * DDIM) {
    float4 f = *(const float4*)(w + i);
    o.x = f2bf(f.x); o.y = f2bf(f.y); o.z = f2bf(f.z); o.w = f2bf(f.w);
  } else {
    o.x = 0; o.y = 0; o.z = 0; o.w = 0;
  }
  *(short4*)(wb + i) = o;
}

// ---------------- K2: sequential tree scan, one block per batch -------------
// thread t: jc = t>>6 (j-chunk of 128), kc = t&63 -> k0 = 16*kc (16 outputs).
// Register sliding window over duplicated+padded rv; invariant:
//   w[(j + r) & 15] == rv2[j + k0 + r]  for r = 0..15
__global__ __launch_bounds__(512) void tree_scan(const int* __restrict__ comp,
                                                 float* __restrict__ vec) {
  __shared__ float lvs[DDIM];
  __shared__ float rvs[2112];        // PAD(2047) = 2110 max
  __shared__ float cstore[DDIM];     // previous step's output (lv reuse)
  __shared__ float partial[8 * 1056];
  __shared__ int infoS[NSTEP * 3];
  __shared__ float redS[8];
  const int b = blockIdx.x, t = threadIdx.x;
  const int jc = t >> 6, k0 = (t & 63) * 16, j0 = jc * 128;
  float* vb = vec + (size_t)b * NNODE * DDIM;
  if (t < NSTEP * 3) infoS[t] = comp[b * NSTEP * 3 + t];
  __syncthreads();
  int prev = -1;
  for (int s = 0; s < NSTEP; ++s) {
    const int i0 = infoS[3 * s], i1 = infoS[3 * s + 1], i2 = infoS[3 * s + 2];
    {
      const float* sl = (i0 == prev) ? cstore : (vb + (size_t)i0 * DDIM);
      lvs[t] = sl[t];
      lvs[t + 512] = sl[t + 512];
      const float* sr = (i1 == prev) ? cstore : (vb + (size_t)i1 * DDIM);
      const float a0 = sr[t], a1 = sr[t + 512];
      rvs[PAD(t)] = a0; rvs[PAD(t + 512)] = a1;
      rvs[PAD(t + 1024)] = a0; rvs[PAD(t + 1536)] = a1;
    }
    __syncthreads();
    float w[16], acc[16];
#pragma unroll
    for (int r = 0; r < 16; ++r) {
      w[r] = rvs[PAD(j0 + k0 + r)];
      acc[r] = 0.f;
    }
    for (int jb = 0; jb < 8; ++jb) {
      const int jbase = j0 + jb * 16;
#pragma unroll
      for (int jj = 0; jj < 16; ++jj) {
        const float a = lvs[jbase + jj];   // wave-uniform broadcast
#pragma unroll
        for (int r = 0; r < 16; ++r) acc[r] += a * w[(jj + r) & 15];
        w[jj] = rvs[PAD(jbase + jj + 16 + k0)];  // refill freed slot
      }
    }
#pragma unroll
    for (int r = 0; r < 16; ++r) partial[jc * 1056 + PAD(k0) + r] = acc[r];
    __syncthreads();
    // reduce 8 j-chunk partials; thread handles k = t and t+512
    const int ka = t, kb = t + 512;
    float c0 = 0.f, c1 = 0.f;
#pragma unroll
    for (int j = 0; j < 8; ++j) {
      c0 += partial[j * 1056 + PAD(ka)];
      c1 += partial[j * 1056 + PAD(kb)];
    }
    float ssq = c0 * c0 + c1 * c1;
#pragma unroll
    for (int off = 32; off > 0; off >>= 1) ssq += __shfl_xor(ssq, off);
    if ((t & 63) == 0) redS[t >> 6] = ssq;
    __syncthreads();
    const float tot = redS[0] + redS[1] + redS[2] + redS[3] +
                      redS[4] + redS[5] + redS[6] + redS[7];
    const float rn = 1.f / (sqrtf(tot) + 1e-6f);
    const float o0 = c0 * rn, o1 = c1 * rn;
    float* dst = vb + (size_t)i2 * DDIM;
    dst[ka] = o0; dst[kb] = o1;
    cstore[ka] = o0; cstore[kb] = o1;
    prev = i2;
    __syncthreads();  // protect lvs/rvs/cstore before next step's staging
  }
}

// ---------------- K4: bf16 MFMA GEMM + bias + sigmoid ------------------------
// C[m][c] = sigmoid( sum_k vec[m][k] * lin_w[c][k] + b[c] )
// 128x128 tile, 4 waves in 2x2, each wave 64x64 = 4x4 frags of 16x16x32 bf16.
__global__ __launch_bounds__(256) void gemm_out(
    const float* __restrict__ A, const short* __restrict__ Bw,
    const float* __restrict__ bias, float* __restrict__ out) {
  __shared__ short As[128 * 64];
  __shared__ short Bs[128 * 64];
  const int t = threadIdx.x;
  const int trow = blockIdx.x * 128, tcol = blockIdx.y * 128;
  const int wv = t >> 6, lane = t & 63;
  const int wr = wv >> 1, wc = wv & 1;
  const int lr = lane & 15, kg = lane >> 4;
  f32x4_t acc[4][4];
  const f32x4_t zz = {0.f, 0.f, 0.f, 0.f};
#pragma unroll
  for (int i = 0; i < 4; ++i)
#pragma unroll
    for (int j = 0; j < 4; ++j) acc[i][j] = zz;

  for (int kt = 0; kt < 16; ++kt) {
    const int kof = kt * 64;
    // A tile stage: 128 rows x 64 cols fp32 -> bf16.
    // 2048 float4-chunks, 256 threads -> q in [0,8).
#pragma unroll
    for (int q = 0; q < 8; ++q) {
      const int c = t + q * 256;
      const int row = c >> 4, colf = (c & 15) * 4;
      float4 f = *(const float4*)(A + (size_t)(trow + row) * DDIM + kof + colf);
      short4 p;
      p.x = f2bf(f.x); p.y = f2bf(f.y); p.z = f2bf(f.z); p.w = f2bf(f.w);
      *(short4*)&As[row * 64 + colf] = p;
    }
    // B tile stage: 128 rows x 64 shorts. 1024 int4-chunks -> q in [0,4).
#pragma unroll
    for (int q = 0; q < 4; ++q) {
      const int c = t + q * 256;
      const int row = c >> 3, coli = (c & 7) * 8;
      *(int4*)&Bs[row * 64 + coli] =
          *(const int4*)(Bw + (size_t)(tcol + row) * DDIM + kof + coli);
    }
    __syncthreads();
#pragma unroll
    for (int kk = 0; kk < 2; ++kk) {
      bf16x8_t af[4], bfr[4];
#pragma unroll
      for (int mi = 0; mi < 4; ++mi)
        af[mi] = *(const bf16x8_t*)&As[(wr * 64 + mi * 16 + lr) * 64 + kk * 32 + kg * 8];
#pragma unroll
      for (int ni = 0; ni < 4; ++ni)
        bfr[ni] = *(const bf16x8_t*)&Bs[(wc * 64 + ni * 16 + lr) * 64 + kk * 32 + kg * 8];
#pragma unroll
      for (int mi = 0; mi < 4; ++mi)
#pragma unroll
        for (int ni = 0; ni < 4; ++ni)
          acc[mi][ni] = __builtin_amdgcn_mfma_f32_16x16x32_bf16(
              af[mi], bfr[ni], acc[mi][ni], 0, 0, 0);
    }
    __syncthreads();
  }
  // epilogue: C/D layout col = lane&15, row = (lane>>4)*4 + reg (m89-verified)
  const int mbase = trow + wr * 64;
  const int nbase = tcol + wc * 64;
#pragma unroll
  for (int ni = 0; ni < 4; ++ni) {
    const int col = nbase + ni * 16 + lr;
    if (col < NCLS) {
      const float bb = bias[col];
#pragma unroll
      for (int mi = 0; mi < 4; ++mi) {
#pragma unroll
        for (int vv = 0; vv < 4; ++vv) {
          const int row = mbase + mi * 16 + kg * 4 + vv;
          const float x = acc[mi][ni][vv] + bb;
          out[(size_t)row * NCLS + col] = 1.f / (1.f + __expf(-x));
        }
      }
    }
  }
}

extern "C" void kernel_launch(void* const* d_in, const int* in_sizes, int n_in,
                              void* d_out, int out_size, void* d_ws, size_t ws_size,
                              hipStream_t stream) {
  const int* ids = (const int*)d_in[0];
  const int* cmask = (const int*)d_in[1];
  const int* comp = (const int*)d_in[2];
  const float* emb = (const float*)d_in[3];
  const float* linw = (const float*)d_in[4];
  const float* linb = (const float*)d_in[5];
  float* out = (float*)d_out;

  char* ws = (char*)d_ws;
  float* vecf = (float*)ws;                                        // 133,169,152 B
  short* linwb = (short*)(ws + (size_t)BATCH * NNODE * DDIM * 4);  //   1,048,576 B

  leaf_init<<<dim3(NNODE, BATCH), 256, 0, stream>>>(ids, cmask, emb, vecf);
  conv_w<<<(NCLSP * DDIM) / 1024, 256, 0, stream>>>(linw, linwb);
  tree_scan<<<BATCH, 512, 0, stream>>>(comp, vecf);
  gemm_out<<<dim3((BATCH * NNODE) / 128, NCLSP / 128), 256, 0, stream>>>(
      vecf, linwb, linb, out);
}

// Round 10
// 760.635 us; speedup vs baseline: 1.2188x; 1.2188x over previous
//
#include <hip/hip_runtime.h>

// Tree_Net: B=256 batches, L=64 leaves, D=1024 dims, N=127 nodes, S=63 compose
// steps, C=500 classes. Pipeline:
//   K1 leaf_init : gather emb rows, mask, L2-normalize -> vec_f32[B][127][1024]
//   K3 conv_w    : lin_w fp32 [500][1024] -> bf16 padded [512][1024]
//   K2 tree_scan : 63 sequential circular-correlation+normalize steps per batch
//                  (fp32, one block per batch; b128 LDS + staggered-block swizzle)
//   K4 gemm_out  : bf16 MFMA 16x16x32 GEMM + bias + sigmoid -> out fp32
// Workspace: vec_f32 = 133,169,152 B ; lin_w bf16 = 1,048,576 B ; total 128 MiB.

#define BATCH 256
#define LLEN 64
#define DDIM 1024
#define NNODE 127
#define NSTEP 63
#define NCLS 500
#define NCLSP 512

// Staggered non-overlapping block layout: 16-float block bi starts at SB(bi).
// Groups of 8 blocks, group stride 160 floats (= 5*128B -> bank-neutral);
// in-group stride 20 floats (80B) -> start banks 20b mod 32 =
// {0,20,8,28,16,4,24,12}: 8 disjoint 4-bank spans covering all 32 banks, so a
// 64-lane ds_read_b128 over 64 consecutive blocks runs at the conflict floor.
// Extents [SB(bi), SB(bi)+16) are disjoint (4-float gap inside groups,
// 20-float gap across groups).
#define SB(bi) ((((bi) >> 3) * 160) + (((bi) & 7) * 20))

typedef __attribute__((ext_vector_type(8))) __bf16 bf16x8_t;
typedef __attribute__((ext_vector_type(4))) float f32x4_t;

__device__ __forceinline__ short f2bf(float f) {
  union { float f; unsigned u; } v; v.f = f;
  unsigned r = v.u + 0x7FFFu + ((v.u >> 16) & 1u);  // RNE, matches HW cvt
  return (short)(r >> 16);
}

// ---------------- K1: leaves gather + mask + normalize; internals zeroed ----
__global__ __launch_bounds__(256) void leaf_init(
    const int* __restrict__ ids, const int* __restrict__ cmask,
    const float* __restrict__ emb, float* __restrict__ vec) {
  const int n = blockIdx.x, b = blockIdx.y, t = threadIdx.x;
  float* dst = vec + ((size_t)b * NNODE + n) * DDIM + 4 * t;
  if (n >= LLEN) {
    float4 z = make_float4(0.f, 0.f, 0.f, 0.f);
    *(float4*)dst = z;
    return;
  }
  __shared__ float sred[4];
  const int id = ids[b * LLEN + n];
  const int m = cmask[b * LLEN + n];
  float4 v = make_float4(0.f, 0.f, 0.f, 0.f);
  if (m > 0) v = *(const float4*)(emb + (size_t)id * DDIM + 4 * t);
  float ss = v.x * v.x + v.y * v.y + v.z * v.z + v.w * v.w;
#pragma unroll
  for (int off = 32; off > 0; off >>= 1) ss += __shfl_xor(ss, off);
  if ((t & 63) == 0) sred[t >> 6] = ss;
  __syncthreads();
  const float tot = sred[0] + sred[1] + sred[2] + sred[3];
  const float rn = 1.f / (sqrtf(tot) + 1e-6f);
  v.x *= rn; v.y *= rn; v.z *= rn; v.w *= rn;
  *(float4*)dst = v;
}

// ---------------- K3: lin_w fp32 -> bf16, padded to 512 rows ----------------
__global__ __launch_bounds__(256) void conv_w(const float* __restrict__ w,
                                              short* __restrict__ wb) {
  const int i = (blockIdx.x * 256 + threadIdx.x) * 4;
  short4 o;
  if (i < NCLS * DDIM) {
    float4 f = *(const float4*)(w + i);
    o.x = f2bf(f.x); o.y = f2bf(f.y); o.z = f2bf(f.z); o.w = f2bf(f.w);
  } else {
    o.x = 0; o.y = 0; o.z = 0; o.w = 0;
  }
  *(short4*)(wb + i) = o;
}

// ---------------- K2: sequential tree scan, one block per batch -------------
// 512 threads: lane = t&63, jc = t>>6 (j-chunk of 128). Thread computes 16
// outputs k0 = 16*(8*jc + lane) ... via block index bi0 = 8*jc + lane.
// rv duplicated into 128 staggered 16-float blocks (rvs). Register window
// W8[8] (f32x4 x8 = 32 floats), invariant at start of jb:
//   w((x + 16*jb) & 31) == rv2[jbase + k0 + x],  x in [0,32), jbase = j0+16*jb
// Per jb: 4 broadcast b128 (lv) + 256 FMA + 4 refill b128. All bulk LDS ops
// b128 at the conflict floor.
__global__ __launch_bounds__(512) void tree_scan(const int* __restrict__ comp,
                                                 float* __restrict__ vec) {
  __shared__ __align__(16) float lvs[DDIM];
  __shared__ __align__(16) float rvs[2560];      // SB(127)+16 = 2556
  __shared__ __align__(16) float cstore[DDIM];   // previous step's output
  __shared__ __align__(16) float part[8 * 1280]; // 8 planes; SB(63)+16 = 1276
  __shared__ int infoS[NSTEP * 3];
  __shared__ float redS[8];
  const int b = blockIdx.x, t = threadIdx.x;
  const int lane = t & 63, jc = t >> 6;
  const int j0 = jc * 128;
  const int bi0 = jc * 8 + lane;  // first window block index for this thread
  float* vb = vec + (size_t)b * NNODE * DDIM;
  if (t < NSTEP * 3) infoS[t] = comp[b * NSTEP * 3 + t];
  __syncthreads();
  int prev = -1;
  for (int s = 0; s < NSTEP; ++s) {
    const int i0 = infoS[3 * s], i1 = infoS[3 * s + 1], i2 = infoS[3 * s + 2];
    // ---- stage lv (skipped when reduce phase pre-wrote it) ----
    if (i0 != prev) {
      const float2 lq = *(const float2*)(vb + (size_t)i0 * DDIM + 2 * t);
      *(float2*)&lvs[2 * t] = lq;
    }
    // ---- stage rv duplicated into staggered blocks ----
    {
      f32x4_t rq;
      if (i1 == prev) rq = *(const f32x4_t*)&cstore[4 * (t & 255)];
      else rq = *(const f32x4_t*)(vb + (size_t)i1 * DDIM + 4 * (t & 255));
      *(f32x4_t*)&rvs[SB(t >> 2) + (t & 3) * 4] = rq;
    }
    __syncthreads();
    // ---- compute ----
    f32x4_t W8[8], acc4[4], av[4];
    {
      const float* w0 = &rvs[SB(bi0)];
      const float* w1 = &rvs[SB(bi0 + 1)];
      W8[0] = *(const f32x4_t*)(w0);
      W8[1] = *(const f32x4_t*)(w0 + 4);
      W8[2] = *(const f32x4_t*)(w0 + 8);
      W8[3] = *(const f32x4_t*)(w0 + 12);
      W8[4] = *(const f32x4_t*)(w1);
      W8[5] = *(const f32x4_t*)(w1 + 4);
      W8[6] = *(const f32x4_t*)(w1 + 8);
      W8[7] = *(const f32x4_t*)(w1 + 12);
    }
    const f32x4_t zz = {0.f, 0.f, 0.f, 0.f};
    acc4[0] = zz; acc4[1] = zz; acc4[2] = zz; acc4[3] = zz;
#pragma unroll
    for (int jb = 0; jb < 8; ++jb) {
      const int jbase = j0 + jb * 16;
      av[0] = *(const f32x4_t*)&lvs[jbase];
      av[1] = *(const f32x4_t*)&lvs[jbase + 4];
      av[2] = *(const f32x4_t*)&lvs[jbase + 8];
      av[3] = *(const f32x4_t*)&lvs[jbase + 12];
#pragma unroll
      for (int jj = 0; jj < 16; ++jj) {
        const float a = av[jj >> 2][jj & 3];
#pragma unroll
        for (int r = 0; r < 16; ++r) {
          const int x = (jj + r + 16 * jb) & 31;  // compile-time constant
          acc4[r >> 2][r & 3] += a * W8[x >> 2][x & 3];
        }
      }
      if (jb < 7) {  // refill the 16 just-freed slots from block bi0+jb+2
        const float* ns = &rvs[SB(bi0 + jb + 2)];
        const int s0 = (jb & 1) ? 4 : 0;
        W8[s0 + 0] = *(const f32x4_t*)(ns);
        W8[s0 + 1] = *(const f32x4_t*)(ns + 4);
        W8[s0 + 2] = *(const f32x4_t*)(ns + 8);
        W8[s0 + 3] = *(const f32x4_t*)(ns + 12);
      }
    }
    {
      float* pw = &part[jc * 1280 + SB(lane)];
      *(f32x4_t*)(pw) = acc4[0];
      *(f32x4_t*)(pw + 4) = acc4[1];
      *(f32x4_t*)(pw + 8) = acc4[2];
      *(f32x4_t*)(pw + 12) = acc4[3];
    }
    __syncthreads();
    // ---- reduce 8 j-chunk partials; thread handles k = t and t+512 ----
    const int ka = t, kb = t + 512;
    const int ba = ka >> 4, oa = ka & 15;
    const int bb = kb >> 4, ob = kb & 15;
    float c0 = 0.f, c1 = 0.f;
#pragma unroll
    for (int j = 0; j < 8; ++j) {
      c0 += part[j * 1280 + SB(ba) + oa];
      c1 += part[j * 1280 + SB(bb) + ob];
    }
    float ssq = c0 * c0 + c1 * c1;
#pragma unroll
    for (int off = 32; off > 0; off >>= 1) ssq += __shfl_xor(ssq, off);
    if ((t & 63) == 0) redS[t >> 6] = ssq;
    __syncthreads();
    const float tot = redS[0] + redS[1] + redS[2] + redS[3] +
                      redS[4] + redS[5] + redS[6] + redS[7];
    const float rn = 1.f / (sqrtf(tot) + 1e-6f);
    const float o0 = c0 * rn, o1 = c1 * rn;
    float* dst = vb + (size_t)i2 * DDIM;
    dst[ka] = o0; dst[kb] = o1;
    cstore[ka] = o0; cstore[kb] = o1;
    if (s + 1 < NSTEP && infoS[3 * (s + 1)] == i2) {  // pre-write next lv
      lvs[ka] = o0; lvs[kb] = o1;
    }
    prev = i2;
    __syncthreads();  // protect lvs/rvs/cstore before next step's staging
  }
}

// ---------------- K4: bf16 MFMA GEMM + bias + sigmoid ------------------------
__global__ __launch_bounds__(256) void gemm_out(
    const float* __restrict__ A, const short* __restrict__ Bw,
    const float* __restrict__ bias, float* __restrict__ out) {
  __shared__ short As[128 * 64];
  __shared__ short Bs[128 * 64];
  const int t = threadIdx.x;
  const int trow = blockIdx.x * 128, tcol = blockIdx.y * 128;
  const int wv = t >> 6, lane = t & 63;
  const int wr = wv >> 1, wc = wv & 1;
  const int lr = lane & 15, kg = lane >> 4;
  f32x4_t acc[4][4];
  const f32x4_t zz = {0.f, 0.f, 0.f, 0.f};
#pragma unroll
  for (int i = 0; i < 4; ++i)
#pragma unroll
    for (int j = 0; j < 4; ++j) acc[i][j] = zz;

  for (int kt = 0; kt < 16; ++kt) {
    const int kof = kt * 64;
#pragma unroll
    for (int q = 0; q < 8; ++q) {
      const int c = t + q * 256;
      const int row = c >> 4, colf = (c & 15) * 4;
      float4 f = *(const float4*)(A + (size_t)(trow + row) * DDIM + kof + colf);
      short4 p;
      p.x = f2bf(f.x); p.y = f2bf(f.y); p.z = f2bf(f.z); p.w = f2bf(f.w);
      *(short4*)&As[row * 64 + colf] = p;
    }
#pragma unroll
    for (int q = 0; q < 4; ++q) {
      const int c = t + q * 256;
      const int row = c >> 3, coli = (c & 7) * 8;
      *(int4*)&Bs[row * 64 + coli] =
          *(const int4*)(Bw + (size_t)(tcol + row) * DDIM + kof + coli);
    }
    __syncthreads();
#pragma unroll
    for (int kk = 0; kk < 2; ++kk) {
      bf16x8_t af[4], bfr[4];
#pragma unroll
      for (int mi = 0; mi < 4; ++mi)
        af[mi] = *(const bf16x8_t*)&As[(wr * 64 + mi * 16 + lr) * 64 + kk * 32 + kg * 8];
#pragma unroll
      for (int ni = 0; ni < 4; ++ni)
        bfr[ni] = *(const bf16x8_t*)&Bs[(wc * 64 + ni * 16 + lr) * 64 + kk * 32 + kg * 8];
#pragma unroll
      for (int mi = 0; mi < 4; ++mi)
#pragma unroll
        for (int ni = 0; ni < 4; ++ni)
          acc[mi][ni] = __builtin_amdgcn_mfma_f32_16x16x32_bf16(
              af[mi], bfr[ni], acc[mi][ni], 0, 0, 0);
    }
    __syncthreads();
  }
  const int mbase = trow + wr * 64;
  const int nbase = tcol + wc * 64;
#pragma unroll
  for (int ni = 0; ni < 4; ++ni) {
    const int col = nbase + ni * 16 + lr;
    if (col < NCLS) {
      const float bb = bias[col];
#pragma unroll
      for (int mi = 0; mi < 4; ++mi) {
#pragma unroll
        for (int vv = 0; vv < 4; ++vv) {
          const int row = mbase + mi * 16 + kg * 4 + vv;
          const float x = acc[mi][ni][vv] + bb;
          out[(size_t)row * NCLS + col] = 1.f / (1.f + __expf(-x));
        }
      }
    }
  }
}

extern "C" void kernel_launch(void* const* d_in, const int* in_sizes, int n_in,
                              void* d_out, int out_size, void* d_ws, size_t ws_size,
                              hipStream_t stream) {
  const int* ids = (const int*)d_in[0];
  const int* cmask = (const int*)d_in[1];
  const int* comp = (const int*)d_in[2];
  const float* emb = (const float*)d_in[3];
  const float* linw = (const float*)d_in[4];
  const float* linb = (const float*)d_in[5];
  float* out = (float*)d_out;

  char* ws = (char*)d_ws;
  float* vecf = (float*)ws;                                        // 133,169,152 B
  short* linwb = (short*)(ws + (size_t)BATCH * NNODE * DDIM * 4);  //   1,048,576 B

  leaf_init<<<dim3(NNODE, BATCH), 256, 0, stream>>>(ids, cmask, emb, vecf);
  conv_w<<<(NCLSP * DDIM) / 1024, 256, 0, stream>>>(linw, linwb);
  tree_scan<<<BATCH, 512, 0, stream>>>(comp, vecf);
  gemm_out<<<dim3((BATCH * NNODE) / 128, NCLSP / 128), 256, 0, stream>>>(
      vecf, linwb, linb, out);
}